// Round 2
// baseline (358.871 us; speedup 1.0000x reference)
//
#include <hip/hip_runtime.h>

typedef unsigned short ushort_t;
typedef __attribute__((ext_vector_type(8))) short bf16x8;   // 8 bf16 (4 VGPRs) MFMA A/B frag
typedef __attribute__((ext_vector_type(4))) float f32x4;    // 16x16 MFMA C/D frag
typedef __attribute__((ext_vector_type(16))) float f32x16;  // 32x32 MFMA C/D frag
typedef __attribute__((ext_vector_type(4))) unsigned short u16x4;
typedef __attribute__((ext_vector_type(2))) int i32x2;

__device__ __forceinline__ ushort_t f2bf(float f) {
  unsigned int u = __float_as_uint(f);
  u += 0x7FFFu + ((u >> 16) & 1u);   // RNE (inputs finite)
  return (ushort_t)(u >> 16);
}

__device__ __forceinline__ int cvt_pk_bf16(float lo, float hi) {
  int r;
  asm("v_cvt_pk_bf16_f32 %0, %1, %2" : "=v"(r) : "v"(lo), "v"(hi));
  return r;
}

__device__ __forceinline__ void gload16(const void* g, void* l) {
  __builtin_amdgcn_global_load_lds((__attribute__((address_space(1))) void*)g,
                                   (__attribute__((address_space(3))) void*)l, 16, 0, 0);
}

// ---------------- prep kernels ----------------

__global__ __launch_bounds__(256) void cast_kernel(const float* __restrict__ in,
                                                   ushort_t* __restrict__ out, int n4) {
  int i = blockIdx.x * 256 + threadIdx.x;
  if (i >= n4) return;
  float4 v = ((const float4*)in)[i];
  u16x4 o = {f2bf(v.x), f2bf(v.y), f2bf(v.z), f2bf(v.w)};
  *(u16x4*)(out + (size_t)i * 4) = o;
}

// fp32 [R][C] -> bf16 [C][R]
__global__ __launch_bounds__(256) void transpose_cast(const float* __restrict__ in,
                                                      ushort_t* __restrict__ out, int R, int C) {
  __shared__ float tile[64][65];
  int c0 = blockIdx.x * 64, r0 = blockIdx.y * 64;
  int tid = threadIdx.x;
  int lr = tid >> 2, q = tid & 3;
  const float* ip = in + (size_t)(r0 + lr) * C + c0 + q * 16;
#pragma unroll
  for (int j = 0; j < 16; ++j) tile[lr][q * 16 + j] = ip[j];
  __syncthreads();
  int oc = tid >> 2;
  ushort_t* op = out + (size_t)(c0 + oc) * R + r0 + q * 16;
#pragma unroll
  for (int j = 0; j < 16; ++j) op[j] = f2bf(tile[q * 16 + j][oc]);
}

// bf16 Vh [bh][2048][64] -> Vt [bh][64][2048]
__global__ __launch_bounds__(256) void transpose_v(const ushort_t* __restrict__ Vh,
                                                   ushort_t* __restrict__ Vt) {
  __shared__ ushort_t tile[64][72];
  int t0 = blockIdx.x * 64, bh = blockIdx.y;
  int tid = threadIdx.x;
  int lr = tid >> 2, q = tid & 3;
  const ushort_t* ip = Vh + ((size_t)bh * 2048 + t0 + lr) * 64 + q * 16;
#pragma unroll
  for (int j = 0; j < 16; ++j) tile[lr][q * 16 + j] = ip[j];
  __syncthreads();
  int d = tid >> 2;
  ushort_t* op = Vt + ((size_t)bh * 64 + d) * 2048 + t0 + q * 16;
#pragma unroll
  for (int j = 0; j < 16; ++j) op[j] = tile[q * 16 + j][d];
}

// ---------------- GEMM: C[M][N] = A[M][K] * Bt[N][K]^T + bias ----------------
// 128x128 tile, BK=32, 4 waves (2x2 of 64x64), m97-style global_load_lds staging.
// MODE 0: write bf16 split Q/K/V [bh][t][d].  MODE 1: write fp32 d_out.

template <int MODE>
__global__ __launch_bounds__(256) void gemm_kernel(
    const ushort_t* __restrict__ A, const ushort_t* __restrict__ Bt,
    const float* __restrict__ bias, float* __restrict__ OutF,
    ushort_t* __restrict__ Qh, ushort_t* __restrict__ Kh, ushort_t* __restrict__ Vh,
    int M, int N, int K) {
  __shared__ __align__(16) char smem[16384];  // A: [0,8192), Bt: [8192,16384)
  const int tid = threadIdx.x;
  const int l = tid & 63;
  const int w = tid >> 6;
  const int m0 = blockIdx.y * 128;
  const int n0 = blockIdx.x * 128;
  const int wr = (w >> 1) * 64;
  const int wc = (w & 1) * 64;

  const f32x4 z = {0.f, 0.f, 0.f, 0.f};
  f32x4 acc[4][4];
#pragma unroll
  for (int i = 0; i < 4; ++i)
#pragma unroll
    for (int j = 0; j < 4; ++j) acc[i][j] = z;

  const int ldsbase = (tid & ~63) * 16;
  for (int kt = 0; kt < K; kt += 32) {
    __syncthreads();
#pragma unroll
    for (int p = 0; p < 2; ++p) {
      int c = p * 256 + tid;
      int row = c >> 2;                         // 64B rows, 4 chunks of 16B
      int gg = (c & 3) ^ ((row >> 1) & 3);      // chunk swizzle (bank-conflict-free frag reads)
      gload16(A + (size_t)(m0 + row) * K + kt + gg * 8, smem + p * 4096 + ldsbase);
      gload16(Bt + (size_t)(n0 + row) * K + kt + gg * 8, smem + 8192 + p * 4096 + ldsbase);
    }
    __syncthreads();
    bf16x8 af[4], bfr[4];
#pragma unroll
    for (int i = 0; i < 4; ++i) {
      int ra = wr + i * 16 + (l & 15);
      af[i] = *(const bf16x8*)(smem + ra * 64 + (((l >> 4) ^ ((ra >> 1) & 3)) << 4));
      int rb = wc + i * 16 + (l & 15);
      bfr[i] = *(const bf16x8*)(smem + 8192 + rb * 64 + (((l >> 4) ^ ((rb >> 1) & 3)) << 4));
    }
#pragma unroll
    for (int mi = 0; mi < 4; ++mi)
#pragma unroll
      for (int ni = 0; ni < 4; ++ni)
        acc[mi][ni] = __builtin_amdgcn_mfma_f32_16x16x32_bf16(af[mi], bfr[ni], acc[mi][ni], 0, 0, 0);
  }

  if (MODE == 0) {
    const int which = n0 >> 10;  // block's 128 cols lie in one of q/k/v
    ushort_t* outp = which == 0 ? Qh : (which == 1 ? Kh : Vh);
#pragma unroll
    for (int ni = 0; ni < 4; ++ni) {
      int col = n0 + wc + ni * 16 + (l & 15);
      float bv = bias[col];
      int cc = col & 1023;
      int h = cc >> 6, d = cc & 63;
#pragma unroll
      for (int mi = 0; mi < 4; ++mi) {
#pragma unroll
        for (int r = 0; r < 4; ++r) {
          int grow = m0 + wr + mi * 16 + (l >> 4) * 4 + r;
          int bb = grow >> 11, t = grow & 2047;
          outp[((size_t)(bb * 16 + h) * 2048 + t) * 64 + d] = f2bf(acc[mi][ni][r] + bv);
        }
      }
    }
  } else {
#pragma unroll
    for (int ni = 0; ni < 4; ++ni) {
      int col = n0 + wc + ni * 16 + (l & 15);
      float bv = bias[col];
#pragma unroll
      for (int mi = 0; mi < 4; ++mi) {
#pragma unroll
        for (int r = 0; r < 4; ++r) {
          int grow = m0 + wr + mi * 16 + (l >> 4) * 4 + r;
          OutF[(size_t)grow * 1024 + col] = acc[mi][ni][r] + bv;
        }
      }
    }
  }
}

// ---------------- flash attention, swapped-operand 32x32 (m214 structure) ----------------
// grid (16 qblocks descending, 64 bh), 256 thr = 4 waves; wave w owns q rows
// a*128 + w*32 .. +32. No LDS, no barriers. Each lane owns ONE q row (col=lane&31
// of the swapped MFMA output); softmax is in-register; PV swapped so O^T keeps
// col=q and alpha-rescale stays lane-uniform.

__global__ __launch_bounds__(256) void attn_kernel(
    const ushort_t* __restrict__ Qh, const ushort_t* __restrict__ Kh,
    const ushort_t* __restrict__ Vt, ushort_t* __restrict__ Y) {
  const int a   = 15 - blockIdx.x;     // big diagonals dispatch first
  const int bh  = blockIdx.y;
  const int tid = threadIdx.x;
  const int l   = tid & 63;
  const int w   = tid >> 6;
  const int q31 = l & 31;
  const int h   = l >> 5;
  const int qw  = a * 128 + w * 32;    // wave's first q row
  const int qg  = qw + q31;            // this lane's q row
  const size_t bK = (size_t)bh * 2048 * 64;

  // Q as B-fragments of mfma(K,Q): lane holds Q[q=l&31][d = i*16 + h*8 + j]
  bf16x8 qf[4];
  {
    const ushort_t* qp = Qh + bK + (size_t)qg * 64 + h * 8;
#pragma unroll
    for (int i = 0; i < 4; ++i) qf[i] = *(const bf16x8*)(qp + i * 16);
  }

  f32x16 o0 = {0.f,0.f,0.f,0.f,0.f,0.f,0.f,0.f,0.f,0.f,0.f,0.f,0.f,0.f,0.f,0.f};
  f32x16 o1 = o0;                       // O^T rows d=0..31 / 32..63, col = own q
  float m = -3e38f, lsum = 0.f;
  const int nt = (qw + 95) >> 6;        // ceil((qw+32)/64) KV tiles for this wave
  const ushort_t* vbase = Vt + (size_t)bh * 64 * 2048 + (size_t)q31 * 2048 + h * 8;

  for (int t = 0; t < nt; ++t) {
    const int kv0 = t * 64;
    // S^T = K · Q^T : A-frag = K rows (lane row = kv0+q31), two 32-k slabs
    const ushort_t* kp = Kh + bK + (size_t)(kv0 + q31) * 64 + h * 8;
    f32x16 s0 = {0.f,0.f,0.f,0.f,0.f,0.f,0.f,0.f,0.f,0.f,0.f,0.f,0.f,0.f,0.f,0.f};
    f32x16 s1 = s0;
#pragma unroll
    for (int i = 0; i < 4; ++i) {
      bf16x8 k0 = *(const bf16x8*)(kp + i * 16);
      bf16x8 k1 = *(const bf16x8*)(kp + 32 * 64 + i * 16);
      s0 = __builtin_amdgcn_mfma_f32_32x32x16_bf16(k0, qf[i], s0, 0, 0, 0);
      s1 = __builtin_amdgcn_mfma_f32_32x32x16_bf16(k1, qf[i], s1, 0, 0, 0);
    }

    // scale + causal mask + row max (lane-local: k = crow(r,h), q fixed)
    float pmax = -3e38f;
    if (kv0 + 63 > qw) {
#pragma unroll
      for (int r = 0; r < 16; ++r) {
        const int crow = (r & 3) + 8 * (r >> 2) + 4 * h;
        float v0 = s0[r] * 0.125f;
        float v1 = s1[r] * 0.125f;
        if (kv0 + crow > qg) v0 = -3e38f;
        if (kv0 + 32 + crow > qg) v1 = -3e38f;
        s0[r] = v0; s1[r] = v1;
        pmax = fmaxf(pmax, fmaxf(v0, v1));
      }
    } else {
#pragma unroll
      for (int r = 0; r < 16; ++r) {
        s0[r] *= 0.125f; s1[r] *= 0.125f;
        pmax = fmaxf(pmax, fmaxf(s0[r], s1[r]));
      }
    }
    pmax = fmaxf(pmax, __shfl_xor(pmax, 32));   // lane pair holds the other 32 k's

    float mn = fmaxf(m, pmax);
    float alpha = __expf(m - mn);
    m = mn;
    float rs = 0.f;
#pragma unroll
    for (int r = 0; r < 16; ++r) {
      float p0 = __expf(s0[r] - m);
      float p1 = __expf(s1[r] - m);
      s0[r] = p0; s1[r] = p1;
      rs += p0 + p1;
    }
    rs += __shfl_xor(rs, 32);
    lsum = lsum * alpha + rs;
#pragma unroll
    for (int r = 0; r < 16; ++r) { o0[r] *= alpha; o1[r] *= alpha; }

    // P^T -> bf16 B-fragments via v_cvt_pk_bf16_f32 + permlane32_swap (T12)
    bf16x8 pa[4];
#pragma unroll
    for (int sl = 0; sl < 2; ++sl) {
      int wd[8];
#pragma unroll
      for (int i = 0; i < 8; ++i)
        wd[i] = sl ? cvt_pk_bf16(s1[2 * i], s1[2 * i + 1])
                   : cvt_pk_bf16(s0[2 * i], s0[2 * i + 1]);
#pragma unroll
      for (int pp = 0; pp < 2; ++pp) {
        i32x2 r0 = __builtin_amdgcn_permlane32_swap(wd[pp * 4 + 0], wd[pp * 4 + 2], false, false);
        i32x2 r1 = __builtin_amdgcn_permlane32_swap(wd[pp * 4 + 1], wd[pp * 4 + 3], false, false);
        union { int i[4]; bf16x8 v; } u;
        u.i[0] = r0[0]; u.i[1] = r1[0]; u.i[2] = r0[1]; u.i[3] = r1[1];
        pa[sl * 2 + pp] = u.v;
      }
    }

    // O^T += V^T · P^T  (A-frag = Vt rows d, B-frag = pa; col of D = own q)
#pragma unroll
    for (int ks = 0; ks < 4; ++ks) {
      bf16x8 va0 = *(const bf16x8*)(vbase + kv0 + ks * 16);
      bf16x8 va1 = *(const bf16x8*)(vbase + 32 * 2048 + kv0 + ks * 16);
      o0 = __builtin_amdgcn_mfma_f32_32x32x16_bf16(va0, pa[ks], o0, 0, 0, 0);
      o1 = __builtin_amdgcn_mfma_f32_32x32x16_bf16(va1, pa[ks], o1, 0, 0, 0);
    }
  }

  // store: lane holds O^T[d = crow(r,h)+32*grp][q = qg] -> Y[b][q][h*64+d]
  const float inv = 1.f / lsum;
  const int b = bh >> 4, hh = bh & 15;
  ushort_t* yp = Y + ((size_t)(b * 2048 + qg)) * 1024 + hh * 64;
#pragma unroll
  for (int grp = 0; grp < 2; ++grp) {
#pragma unroll
    for (int rg = 0; rg < 4; ++rg) {
      int d0 = grp * 32 + rg * 8 + h * 4;
      u16x4 pk;
#pragma unroll
      for (int j = 0; j < 4; ++j)
        pk[j] = f2bf((grp ? o1[rg * 4 + j] : o0[rg * 4 + j]) * inv);
      *(u16x4*)(yp + d0) = pk;
    }
  }
}

// ---------------- launch ----------------

extern "C" void kernel_launch(void* const* d_in, const int* in_sizes, int n_in,
                              void* d_out, int out_size, void* d_ws, size_t ws_size,
                              hipStream_t stream) {
  const float* x      = (const float*)d_in[0];
  const float* w_qkv  = (const float*)d_in[1];
  const float* b_qkv  = (const float*)d_in[2];
  const float* w_proj = (const float*)d_in[3];
  const float* b_proj = (const float*)d_in[4];
  float* out = (float*)d_out;

  char* ws = (char*)d_ws;
  ushort_t* xb = (ushort_t*)(ws + 0);            // 16 MB  x bf16 [8192][1024]; reused as y after attn
  ushort_t* Wq = (ushort_t*)(ws + (16u << 20));  //  6 MB  w_qkv^T bf16 [3072][1024]
  ushort_t* Wp = (ushort_t*)(ws + (22u << 20));  //  2 MB  w_proj^T bf16 [1024][1024]
  ushort_t* Qh = (ushort_t*)(ws + (24u << 20));  // 16 MB  [64][2048][64]
  ushort_t* Kh = (ushort_t*)(ws + (40u << 20));  // 16 MB
  ushort_t* Vh = (ushort_t*)(ws + (56u << 20));  // 16 MB
  ushort_t* Vt = (ushort_t*)(ws + (72u << 20));  // 16 MB  [64][64][2048]

  cast_kernel<<<8192, 256, 0, stream>>>(x, xb, 2097152);
  transpose_cast<<<dim3(48, 16), 256, 0, stream>>>(w_qkv, Wq, 1024, 3072);
  transpose_cast<<<dim3(16, 16), 256, 0, stream>>>(w_proj, Wp, 1024, 1024);

  gemm_kernel<0><<<dim3(24, 64), 256, 0, stream>>>(xb, Wq, b_qkv, nullptr, Qh, Kh, Vh,
                                                   8192, 3072, 1024);
  transpose_v<<<dim3(32, 64), 256, 0, stream>>>(Vh, Vt);
  attn_kernel<<<dim3(16, 64), 256, 0, stream>>>(Qh, Kh, Vt, xb /* y overwrites x_bf16 */);
  gemm_kernel<1><<<dim3(8, 64), 256, 0, stream>>>(xb, Wp, b_proj, out, nullptr, nullptr, nullptr,
                                                  8192, 1024, 1024);
}

// Round 3
// 255.308 us; speedup vs baseline: 1.4056x; 1.4056x over previous
//
#include <hip/hip_runtime.h>

typedef unsigned short ushort_t;
typedef __attribute__((ext_vector_type(8))) short bf16x8;   // 8 bf16 (4 VGPRs) MFMA A/B frag
typedef __attribute__((ext_vector_type(4))) float f32x4;    // 16x16 MFMA C/D frag
typedef __attribute__((ext_vector_type(16))) float f32x16;  // 32x32 MFMA C/D frag
typedef __attribute__((ext_vector_type(4))) unsigned short u16x4;
typedef __attribute__((ext_vector_type(2))) int i32x2;

__device__ __forceinline__ ushort_t f2bf(float f) {
  unsigned int u = __float_as_uint(f);
  u += 0x7FFFu + ((u >> 16) & 1u);   // RNE (inputs finite)
  return (ushort_t)(u >> 16);
}

__device__ __forceinline__ int cvt_pk_bf16(float lo, float hi) {
  int r;
  asm("v_cvt_pk_bf16_f32 %0, %1, %2" : "=v"(r) : "v"(lo), "v"(hi));
  return r;
}

__device__ __forceinline__ void gload16(const void* g, void* l) {
  __builtin_amdgcn_global_load_lds((__attribute__((address_space(1))) void*)g,
                                   (__attribute__((address_space(3))) void*)l, 16, 0, 0);
}

// ---------------- prep kernels ----------------

__global__ __launch_bounds__(256) void cast_kernel(const float* __restrict__ in,
                                                   ushort_t* __restrict__ out, int n4) {
  int i = blockIdx.x * 256 + threadIdx.x;
  if (i >= n4) return;
  float4 v = ((const float4*)in)[i];
  u16x4 o = {f2bf(v.x), f2bf(v.y), f2bf(v.z), f2bf(v.w)};
  *(u16x4*)(out + (size_t)i * 4) = o;
}

// fp32 [R][C] -> bf16 [C][R]
__global__ __launch_bounds__(256) void transpose_cast(const float* __restrict__ in,
                                                      ushort_t* __restrict__ out, int R, int C) {
  __shared__ float tile[64][65];
  int c0 = blockIdx.x * 64, r0 = blockIdx.y * 64;
  int tid = threadIdx.x;
  int lr = tid >> 2, q = tid & 3;
  const float* ip = in + (size_t)(r0 + lr) * C + c0 + q * 16;
#pragma unroll
  for (int j = 0; j < 16; ++j) tile[lr][q * 16 + j] = ip[j];
  __syncthreads();
  int oc = tid >> 2;
  ushort_t* op = out + (size_t)(c0 + oc) * R + r0 + q * 16;
#pragma unroll
  for (int j = 0; j < 16; ++j) op[j] = f2bf(tile[q * 16 + j][oc]);
}

// bf16 Vh [bh][2048][64] -> Vt [bh][64][2048]
__global__ __launch_bounds__(256) void transpose_v(const ushort_t* __restrict__ Vh,
                                                   ushort_t* __restrict__ Vt) {
  __shared__ ushort_t tile[64][72];
  int t0 = blockIdx.x * 64, bh = blockIdx.y;
  int tid = threadIdx.x;
  int lr = tid >> 2, q = tid & 3;
  const ushort_t* ip = Vh + ((size_t)bh * 2048 + t0 + lr) * 64 + q * 16;
#pragma unroll
  for (int j = 0; j < 16; ++j) tile[lr][q * 16 + j] = ip[j];
  __syncthreads();
  int d = tid >> 2;
  ushort_t* op = Vt + ((size_t)bh * 64 + d) * 2048 + t0 + q * 16;
#pragma unroll
  for (int j = 0; j < 16; ++j) op[j] = tile[q * 16 + j][d];
}

// ---------------- GEMM: C[M][N] = A[M][K] * Bt[N][K]^T + bias ----------------

template <int MODE>
__global__ __launch_bounds__(256) void gemm_kernel(
    const ushort_t* __restrict__ A, const ushort_t* __restrict__ Bt,
    const float* __restrict__ bias, float* __restrict__ OutF,
    ushort_t* __restrict__ Qh, ushort_t* __restrict__ Kh, ushort_t* __restrict__ Vh,
    int M, int N, int K) {
  __shared__ __align__(16) char smem[16384];  // A: [0,8192), Bt: [8192,16384)
  const int tid = threadIdx.x;
  const int l = tid & 63;
  const int w = tid >> 6;
  const int m0 = blockIdx.y * 128;
  const int n0 = blockIdx.x * 128;
  const int wr = (w >> 1) * 64;
  const int wc = (w & 1) * 64;

  const f32x4 z = {0.f, 0.f, 0.f, 0.f};
  f32x4 acc[4][4];
#pragma unroll
  for (int i = 0; i < 4; ++i)
#pragma unroll
    for (int j = 0; j < 4; ++j) acc[i][j] = z;

  const int ldsbase = (tid & ~63) * 16;
  for (int kt = 0; kt < K; kt += 32) {
    __syncthreads();
#pragma unroll
    for (int p = 0; p < 2; ++p) {
      int c = p * 256 + tid;
      int row = c >> 2;                         // 64B rows, 4 chunks of 16B
      int gg = (c & 3) ^ ((row >> 1) & 3);      // chunk swizzle
      gload16(A + (size_t)(m0 + row) * K + kt + gg * 8, smem + p * 4096 + ldsbase);
      gload16(Bt + (size_t)(n0 + row) * K + kt + gg * 8, smem + 8192 + p * 4096 + ldsbase);
    }
    __syncthreads();
    bf16x8 af[4], bfr[4];
#pragma unroll
    for (int i = 0; i < 4; ++i) {
      int ra = wr + i * 16 + (l & 15);
      af[i] = *(const bf16x8*)(smem + ra * 64 + (((l >> 4) ^ ((ra >> 1) & 3)) << 4));
      int rb = wc + i * 16 + (l & 15);
      bfr[i] = *(const bf16x8*)(smem + 8192 + rb * 64 + (((l >> 4) ^ ((rb >> 1) & 3)) << 4));
    }
#pragma unroll
    for (int mi = 0; mi < 4; ++mi)
#pragma unroll
      for (int ni = 0; ni < 4; ++ni)
        acc[mi][ni] = __builtin_amdgcn_mfma_f32_16x16x32_bf16(af[mi], bfr[ni], acc[mi][ni], 0, 0, 0);
  }

  if (MODE == 0) {
    const int which = n0 >> 10;  // block's 128 cols lie in one of q/k/v
    ushort_t* outp = which == 0 ? Qh : (which == 1 ? Kh : Vh);
#pragma unroll
    for (int ni = 0; ni < 4; ++ni) {
      int col = n0 + wc + ni * 16 + (l & 15);
      float bv = bias[col];
      int cc = col & 1023;
      int h = cc >> 6, d = cc & 63;
#pragma unroll
      for (int mi = 0; mi < 4; ++mi) {
#pragma unroll
        for (int r = 0; r < 4; ++r) {
          int grow = m0 + wr + mi * 16 + (l >> 4) * 4 + r;
          int bb = grow >> 11, t = grow & 2047;
          outp[((size_t)(bb * 16 + h) * 2048 + t) * 64 + d] = f2bf(acc[mi][ni][r] + bv);
        }
      }
    }
  } else {
#pragma unroll
    for (int ni = 0; ni < 4; ++ni) {
      int col = n0 + wc + ni * 16 + (l & 15);
      float bv = bias[col];
#pragma unroll
      for (int mi = 0; mi < 4; ++mi) {
#pragma unroll
        for (int r = 0; r < 4; ++r) {
          int grow = m0 + wr + mi * 16 + (l >> 4) * 4 + r;
          OutF[(size_t)grow * 1024 + col] = acc[mi][ni][r] + bv;
        }
      }
    }
  }
}

// ---------------- flash attention, swapped-operand 32x32, latency-pipelined ----------------
// grid 2048 linear, 128 thr = 2 waves. Decode: bh ≡ id (mod 8) -> all q-blocks of a
// head pin to one XCD (8 heads x 512KB KV = 4MB = one L2). q-tiles big-first.
// KVBLK=32: per tile 4 K-frag + 4 V-frag loads; V issued at iter top (consumed after
// softmax), next-tile K prefetched a full iteration ahead (T14). T13 defer-max,
// exp2-domain softmax, T5 setprio around MFMA.

#define ATTN_TILE(KV0, KF, MASKED, PREF)                                        \
  do {                                                                          \
    const int kv0_ = (KV0);                                                     \
    vc[0] = *(const bf16x8*)(vbase + kv0_);                                     \
    vc[1] = *(const bf16x8*)(vbase + kv0_ + 16);                                \
    vc[2] = *(const bf16x8*)(vbase + 65536 + kv0_);                             \
    vc[3] = *(const bf16x8*)(vbase + 65536 + kv0_ + 16);                        \
    if (PREF) {                                                                 \
      _Pragma("unroll")                                                         \
      for (int i = 0; i < 4; ++i)                                               \
        kn[i] = *(const bf16x8*)(kbase + (size_t)(kv0_ + 32) * 64 + i * 16);    \
    }                                                                           \
    f32x16 s = fz;                                                              \
    __builtin_amdgcn_s_setprio(1);                                              \
    _Pragma("unroll")                                                           \
    for (int i = 0; i < 4; ++i)                                                 \
      s = __builtin_amdgcn_mfma_f32_32x32x16_bf16(KF[i], qf[i], s, 0, 0, 0);    \
    __builtin_amdgcn_s_setprio(0);                                              \
    float pmax = -3e38f;                                                        \
    _Pragma("unroll")                                                           \
    for (int r = 0; r < 16; ++r) {                                              \
      float sv = s[r] * SC;                                                     \
      if (MASKED) {                                                             \
        int crow = (r & 3) + 8 * (r >> 2) + 4 * h;                              \
        if (kv0_ + crow > qg) sv = -3e38f;                                      \
      }                                                                         \
      s[r] = sv;                                                                \
      pmax = fmaxf(pmax, sv);                                                   \
    }                                                                           \
    pmax = fmaxf(pmax, __shfl_xor(pmax, 32));                                   \
    if (__any(pmax > m + 8.f)) {                                                \
      float mn = fmaxf(m, pmax);                                                \
      float al = __builtin_amdgcn_exp2f(m - mn);                                \
      m = mn;                                                                   \
      lsum *= al;                                                               \
      _Pragma("unroll")                                                         \
      for (int r = 0; r < 16; ++r) { o0[r] *= al; o1[r] *= al; }                \
    }                                                                           \
    float rs = 0.f;                                                             \
    _Pragma("unroll")                                                           \
    for (int r = 0; r < 16; ++r) {                                              \
      float p = __builtin_amdgcn_exp2f(s[r] - m);                               \
      s[r] = p;                                                                 \
      rs += p;                                                                  \
    }                                                                           \
    rs += __shfl_xor(rs, 32);                                                   \
    lsum += rs;                                                                 \
    int wd[8];                                                                  \
    _Pragma("unroll")                                                           \
    for (int i = 0; i < 8; ++i) wd[i] = cvt_pk_bf16(s[2 * i], s[2 * i + 1]);    \
    bf16x8 pa[2];                                                               \
    _Pragma("unroll")                                                           \
    for (int pp = 0; pp < 2; ++pp) {                                            \
      i32x2 r0 = __builtin_amdgcn_permlane32_swap(wd[pp * 4 + 0], wd[pp * 4 + 2], false, false); \
      i32x2 r1 = __builtin_amdgcn_permlane32_swap(wd[pp * 4 + 1], wd[pp * 4 + 3], false, false); \
      union { int i[4]; bf16x8 v; } u;                                          \
      u.i[0] = r0[0]; u.i[1] = r1[0]; u.i[2] = r0[1]; u.i[3] = r1[1];           \
      pa[pp] = u.v;                                                             \
    }                                                                           \
    __builtin_amdgcn_s_setprio(1);                                              \
    o0 = __builtin_amdgcn_mfma_f32_32x32x16_bf16(vc[0], pa[0], o0, 0, 0, 0);    \
    o0 = __builtin_amdgcn_mfma_f32_32x32x16_bf16(vc[1], pa[1], o0, 0, 0, 0);    \
    o1 = __builtin_amdgcn_mfma_f32_32x32x16_bf16(vc[2], pa[0], o1, 0, 0, 0);    \
    o1 = __builtin_amdgcn_mfma_f32_32x32x16_bf16(vc[3], pa[1], o1, 0, 0, 0);    \
    __builtin_amdgcn_s_setprio(0);                                              \
  } while (0)

__global__ __launch_bounds__(128, 3) void attn_kernel(
    const ushort_t* __restrict__ Qh, const ushort_t* __restrict__ Kh,
    const ushort_t* __restrict__ Vt, ushort_t* __restrict__ Y) {
  const int id  = blockIdx.x;                       // 0..2047
  const int bh  = (id & 7) | (((id >> 3) & 7) << 3);  // bh ≡ id (mod 8): XCD-pinned head
  const int qi  = 31 - (id >> 6);                   // big diagonals first
  const int tid = threadIdx.x;
  const int l   = tid & 63;
  const int w   = tid >> 6;                         // 0..1
  const int q31 = l & 31;
  const int h   = l >> 5;
  const int qw  = qi * 64 + w * 32;                 // wave's first q row
  const int qg  = qw + q31;                         // this lane's q row
  const size_t bK = (size_t)bh * (2048 * 64);
  const float SC = 0.18033688f;                     // 0.125 * log2(e)

  bf16x8 qf[4];
  {
    const ushort_t* qp = Qh + bK + (size_t)qg * 64 + h * 8;
#pragma unroll
    for (int i = 0; i < 4; ++i) qf[i] = *(const bf16x8*)(qp + i * 16);
  }

  const f32x16 fz = {0.f,0.f,0.f,0.f,0.f,0.f,0.f,0.f,0.f,0.f,0.f,0.f,0.f,0.f,0.f,0.f};
  f32x16 o0 = fz, o1 = fz;          // O^T rows d=0..31 / 32..63, col = own q
  float m = -3e38f, lsum = 0.f;
  const int nt = (qw >> 5) + 1;     // 32-wide KV tiles incl. diagonal
  const ushort_t* kbase = Kh + bK + (size_t)q31 * 64 + h * 8;
  const ushort_t* vbase = Vt + (size_t)bh * (64 * 2048) + (size_t)q31 * 2048 + h * 8;

  bf16x8 kc[4], kn[4], vc[4];
#pragma unroll
  for (int i = 0; i < 4; ++i) kc[i] = *(const bf16x8*)(kbase + i * 16);

  for (int t = 0; t < nt - 1; ++t) {
    ATTN_TILE(t * 32, kc, false, true);
#pragma unroll
    for (int i = 0; i < 4; ++i) kc[i] = kn[i];
  }
  ATTN_TILE(qw, kc, true, false);   // diagonal tile, causal-masked

  const float inv = 1.f / lsum;
  const int b = bh >> 4, hh = bh & 15;
  ushort_t* yp = Y + ((size_t)(b * 2048 + qg)) * 1024 + hh * 64;
#pragma unroll
  for (int grp = 0; grp < 2; ++grp) {
#pragma unroll
    for (int rg = 0; rg < 4; ++rg) {
      int d0 = grp * 32 + rg * 8 + h * 4;
      u16x4 pk;
#pragma unroll
      for (int j = 0; j < 4; ++j)
        pk[j] = f2bf((grp ? o1[rg * 4 + j] : o0[rg * 4 + j]) * inv);
      *(u16x4*)(yp + d0) = pk;
    }
  }
}

// ---------------- launch ----------------

extern "C" void kernel_launch(void* const* d_in, const int* in_sizes, int n_in,
                              void* d_out, int out_size, void* d_ws, size_t ws_size,
                              hipStream_t stream) {
  const float* x      = (const float*)d_in[0];
  const float* w_qkv  = (const float*)d_in[1];
  const float* b_qkv  = (const float*)d_in[2];
  const float* w_proj = (const float*)d_in[3];
  const float* b_proj = (const float*)d_in[4];
  float* out = (float*)d_out;

  char* ws = (char*)d_ws;
  ushort_t* xb = (ushort_t*)(ws + 0);            // 16 MB  x bf16 [8192][1024]; reused as y after attn
  ushort_t* Wq = (ushort_t*)(ws + (16u << 20));  //  6 MB  w_qkv^T bf16 [3072][1024]
  ushort_t* Wp = (ushort_t*)(ws + (22u << 20));  //  2 MB  w_proj^T bf16 [1024][1024]
  ushort_t* Qh = (ushort_t*)(ws + (24u << 20));  // 16 MB  [64][2048][64]
  ushort_t* Kh = (ushort_t*)(ws + (40u << 20));  // 16 MB
  ushort_t* Vh = (ushort_t*)(ws + (56u << 20));  // 16 MB
  ushort_t* Vt = (ushort_t*)(ws + (72u << 20));  // 16 MB  [64][64][2048]

  cast_kernel<<<8192, 256, 0, stream>>>(x, xb, 2097152);
  transpose_cast<<<dim3(48, 16), 256, 0, stream>>>(w_qkv, Wq, 1024, 3072);
  transpose_cast<<<dim3(16, 16), 256, 0, stream>>>(w_proj, Wp, 1024, 1024);

  gemm_kernel<0><<<dim3(24, 64), 256, 0, stream>>>(xb, Wq, b_qkv, nullptr, Qh, Kh, Vh,
                                                   8192, 3072, 1024);
  transpose_v<<<dim3(32, 64), 256, 0, stream>>>(Vh, Vt);
  attn_kernel<<<2048, 128, 0, stream>>>(Qh, Kh, Vt, xb /* y overwrites x_bf16 */);
  gemm_kernel<1><<<dim3(8, 64), 256, 0, stream>>>(xb, Wp, b_proj, out, nullptr, nullptr, nullptr,
                                                  8192, 1024, 1024);
}

// Round 4
// 194.186 us; speedup vs baseline: 1.8481x; 1.3148x over previous
//
#include <hip/hip_runtime.h>

typedef unsigned short ushort_t;
typedef __attribute__((ext_vector_type(8))) short bf16x8;   // 8 bf16 (4 VGPRs) MFMA A/B frag
typedef __attribute__((ext_vector_type(4))) float f32x4;    // 16x16 MFMA C/D frag
typedef __attribute__((ext_vector_type(16))) float f32x16;  // 32x32 MFMA C/D frag
typedef __attribute__((ext_vector_type(4))) unsigned short u16x4;
typedef __attribute__((ext_vector_type(2))) int i32x2;

__device__ __forceinline__ ushort_t f2bf(float f) {
  unsigned int u = __float_as_uint(f);
  u += 0x7FFFu + ((u >> 16) & 1u);   // RNE (inputs finite)
  return (ushort_t)(u >> 16);
}

__device__ __forceinline__ int cvt_pk_bf16(float lo, float hi) {
  int r;
  asm("v_cvt_pk_bf16_f32 %0, %1, %2" : "=v"(r) : "v"(lo), "v"(hi));
  return r;
}

__device__ __forceinline__ void gload16(const void* g, void* l) {
  __builtin_amdgcn_global_load_lds((__attribute__((address_space(1))) void*)g,
                                   (__attribute__((address_space(3))) void*)l, 16, 0, 0);
}

// ---------------- prep kernels ----------------

__global__ __launch_bounds__(256) void cast_kernel(const float* __restrict__ in,
                                                   ushort_t* __restrict__ out, int n4) {
  int i = blockIdx.x * 256 + threadIdx.x;
  if (i >= n4) return;
  float4 v = ((const float4*)in)[i];
  u16x4 o = {f2bf(v.x), f2bf(v.y), f2bf(v.z), f2bf(v.w)};
  *(u16x4*)(out + (size_t)i * 4) = o;
}

// fp32 [R][C] -> bf16 [C][R]
__global__ __launch_bounds__(256) void transpose_cast(const float* __restrict__ in,
                                                      ushort_t* __restrict__ out, int R, int C) {
  __shared__ float tile[64][65];
  int c0 = blockIdx.x * 64, r0 = blockIdx.y * 64;
  int tid = threadIdx.x;
  int lr = tid >> 2, q = tid & 3;
  const float* ip = in + (size_t)(r0 + lr) * C + c0 + q * 16;
#pragma unroll
  for (int j = 0; j < 16; ++j) tile[lr][q * 16 + j] = ip[j];
  __syncthreads();
  int oc = tid >> 2;
  ushort_t* op = out + (size_t)(c0 + oc) * R + r0 + q * 16;
#pragma unroll
  for (int j = 0; j < 16; ++j) op[j] = f2bf(tile[q * 16 + j][oc]);
}

// bf16 Vh [bh][2048][64] -> Vt [bh][64][2048]
__global__ __launch_bounds__(256) void transpose_v(const ushort_t* __restrict__ Vh,
                                                   ushort_t* __restrict__ Vt) {
  __shared__ ushort_t tile[64][72];
  int t0 = blockIdx.x * 64, bh = blockIdx.y;
  int tid = threadIdx.x;
  int lr = tid >> 2, q = tid & 3;
  const ushort_t* ip = Vh + ((size_t)bh * 2048 + t0 + lr) * 64 + q * 16;
#pragma unroll
  for (int j = 0; j < 16; ++j) tile[lr][q * 16 + j] = ip[j];
  __syncthreads();
  int d = tid >> 2;
  ushort_t* op = Vt + ((size_t)bh * 64 + d) * 2048 + t0 + q * 16;
#pragma unroll
  for (int j = 0; j < 16; ++j) op[j] = tile[q * 16 + j][d];
}

// ---------------- GEMM: C[M][N] = A[M][K] * Bt[N][K]^T + bias ----------------

template <int MODE>
__global__ __launch_bounds__(256) void gemm_kernel(
    const ushort_t* __restrict__ A, const ushort_t* __restrict__ Bt,
    const float* __restrict__ bias, float* __restrict__ OutF,
    ushort_t* __restrict__ Qh, ushort_t* __restrict__ Kh, ushort_t* __restrict__ Vh,
    int M, int N, int K) {
  __shared__ __align__(16) char smem[16384];  // A: [0,8192), Bt: [8192,16384)
  const int tid = threadIdx.x;
  const int l = tid & 63;
  const int w = tid >> 6;
  const int m0 = blockIdx.y * 128;
  const int n0 = blockIdx.x * 128;
  const int wr = (w >> 1) * 64;
  const int wc = (w & 1) * 64;

  const f32x4 z = {0.f, 0.f, 0.f, 0.f};
  f32x4 acc[4][4];
#pragma unroll
  for (int i = 0; i < 4; ++i)
#pragma unroll
    for (int j = 0; j < 4; ++j) acc[i][j] = z;

  const int ldsbase = (tid & ~63) * 16;
  for (int kt = 0; kt < K; kt += 32) {
    __syncthreads();
#pragma unroll
    for (int p = 0; p < 2; ++p) {
      int c = p * 256 + tid;
      int row = c >> 2;                         // 64B rows, 4 chunks of 16B
      int gg = (c & 3) ^ ((row >> 1) & 3);      // chunk swizzle
      gload16(A + (size_t)(m0 + row) * K + kt + gg * 8, smem + p * 4096 + ldsbase);
      gload16(Bt + (size_t)(n0 + row) * K + kt + gg * 8, smem + 8192 + p * 4096 + ldsbase);
    }
    __syncthreads();
    bf16x8 af[4], bfr[4];
#pragma unroll
    for (int i = 0; i < 4; ++i) {
      int ra = wr + i * 16 + (l & 15);
      af[i] = *(const bf16x8*)(smem + ra * 64 + (((l >> 4) ^ ((ra >> 1) & 3)) << 4));
      int rb = wc + i * 16 + (l & 15);
      bfr[i] = *(const bf16x8*)(smem + 8192 + rb * 64 + (((l >> 4) ^ ((rb >> 1) & 3)) << 4));
    }
#pragma unroll
    for (int mi = 0; mi < 4; ++mi)
#pragma unroll
      for (int ni = 0; ni < 4; ++ni)
        acc[mi][ni] = __builtin_amdgcn_mfma_f32_16x16x32_bf16(af[mi], bfr[ni], acc[mi][ni], 0, 0, 0);
  }

  if (MODE == 0) {
    const int which = n0 >> 10;  // block's 128 cols lie in one of q/k/v
    ushort_t* outp = which == 0 ? Qh : (which == 1 ? Kh : Vh);
#pragma unroll
    for (int ni = 0; ni < 4; ++ni) {
      int col = n0 + wc + ni * 16 + (l & 15);
      float bv = bias[col];
      int cc = col & 1023;
      int h = cc >> 6, d = cc & 63;
#pragma unroll
      for (int mi = 0; mi < 4; ++mi) {
#pragma unroll
        for (int r = 0; r < 4; ++r) {
          int grow = m0 + wr + mi * 16 + (l >> 4) * 4 + r;
          int bb = grow >> 11, t = grow & 2047;
          outp[((size_t)(bb * 16 + h) * 2048 + t) * 64 + d] = f2bf(acc[mi][ni][r] + bv);
        }
      }
    }
  } else {
#pragma unroll
    for (int ni = 0; ni < 4; ++ni) {
      int col = n0 + wc + ni * 16 + (l & 15);
      float bv = bias[col];
#pragma unroll
      for (int mi = 0; mi < 4; ++mi) {
#pragma unroll
        for (int r = 0; r < 4; ++r) {
          int grow = m0 + wr + mi * 16 + (l >> 4) * 4 + r;
          OutF[(size_t)grow * 1024 + col] = acc[mi][ni][r] + bv;
        }
      }
    }
  }
}

// ---------------- flash attention, 8-wave LDS-cooperative (m214-shape) ----------------
// grid 512, 512 thr = 8 waves. Block = (bh, 256-q super-tile); wave w owns q rows
// q0+32w..+32 with the verified swapped-QK^T in-register softmax. K/V staged once per
// block per 64-wide KV tile via global_load_lds (coalesced), double-buffered,
// XOR-swizzled (pre-swizzled global src + swizzled ds_read — rule 21). One barrier
// per tile; stage(t+1) issued before compute(t). Waves skip compute (not barriers)
// past their diagonal. XCD pinning: 8 heads per XCD.

__global__ __launch_bounds__(512, 4) void attn_kernel(
    const ushort_t* __restrict__ Qh, const ushort_t* __restrict__ Kh,
    const ushort_t* __restrict__ Vt, ushort_t* __restrict__ Y) {
  __shared__ __align__(16) char smem[32768];   // 2 bufs x (K 8KB + V 8KB)
  const int id  = blockIdx.x;                  // 0..511
  const int x   = id & 7;                      // XCD lane
  const int g   = id >> 3;                     // 0..63
  const int bh  = x * 8 + (g & 7);             // 8 heads pinned per XCD
  const int qs  = 7 - (g >> 3);                // 256-q super-tile, big-first
  const int q0  = qs * 256;
  const int tid = threadIdx.x;
  const int l   = tid & 63;
  const int w   = tid >> 6;                    // 0..7
  const int q31 = l & 31;
  const int h   = l >> 5;
  const int qw  = q0 + w * 32;
  const int qg  = qw + q31;
  const size_t bK = (size_t)bh * (2048 * 64);
  const float SC = 0.18033688f;                // 0.125 * log2(e)

  // staging addresses: thread tid loads 16B chunk; row = tid>>3, swizzled col
  const int srow = tid >> 3;
  const int scol = (((tid & 7) << 4) ^ ((srow & 7) << 4)) >> 1;  // element offset
  const ushort_t* ksrc = Kh + bK + (size_t)srow * 64 + scol;
  const ushort_t* vsrc = Vt + (size_t)bh * (64 * 2048) + (size_t)srow * 2048 + scol;
  char* const dstK = smem + w * 1024;          // HW adds lane*16
  char* const dstV = smem + 8192 + w * 1024;

  // per-wave LDS fragment read bases (row = q31, swizzled)
  const int fsw = ((q31 & 7) << 4);
  const int kfb = q31 * 128;                   // + (i*32 + h*16)^fsw  [+4096 slab1]
  bf16x8 qf[4];
  {
    const ushort_t* qp = Qh + bK + (size_t)qg * 64 + h * 8;
#pragma unroll
    for (int i = 0; i < 4; ++i) qf[i] = *(const bf16x8*)(qp + i * 16);
  }

  const f32x16 fz = {0.f,0.f,0.f,0.f,0.f,0.f,0.f,0.f,0.f,0.f,0.f,0.f,0.f,0.f,0.f,0.f};
  f32x16 o0 = fz, o1 = fz;
  float m = -3e38f, lsum = 0.f;
  const int nkv = qs * 4 + 4;

  // prologue: stage tile 0 into buf 0
  gload16(ksrc, dstK);
  gload16(vsrc + 0, dstV);
  __syncthreads();

  int cur = 0;
  for (int t = 0; t < nkv; ++t) {
    const int kv0 = t * 64;
    // stage next tile into the other buffer (async; barrier at loop end drains)
    if (t + 1 < nkv) {
      gload16(ksrc + (size_t)(kv0 + 64) * 64, dstK + (cur ^ 1) * 16384);
      gload16(vsrc + kv0 + 64, dstV + (cur ^ 1) * 16384);
    }
    if (kv0 <= qw + 31) {                      // wave-uniform compute gate
      const char* kb = smem + cur * 16384;
      const char* vb = kb + 8192;
      // S^T = K · Q^T, two 32-row slabs
      f32x16 s0 = fz, s1 = fz;
      __builtin_amdgcn_s_setprio(1);
#pragma unroll
      for (int i = 0; i < 4; ++i) {
        bf16x8 k0 = *(const bf16x8*)(kb + kfb + ((i * 32 + h * 16) ^ fsw));
        bf16x8 k1 = *(const bf16x8*)(kb + 4096 + kfb + ((i * 32 + h * 16) ^ fsw));
        s0 = __builtin_amdgcn_mfma_f32_32x32x16_bf16(k0, qf[i], s0, 0, 0, 0);
        s1 = __builtin_amdgcn_mfma_f32_32x32x16_bf16(k1, qf[i], s1, 0, 0, 0);
      }
      __builtin_amdgcn_s_setprio(0);

      // mask (raw domain) + raw max
      float pmax = -3e38f;
      if (kv0 + 63 > qw) {
#pragma unroll
        for (int r = 0; r < 16; ++r) {
          const int crow = (r & 3) + 8 * (r >> 2) + 4 * h;
          if (kv0 + crow > qg) s0[r] = -3e38f;
          if (kv0 + 32 + crow > qg) s1[r] = -3e38f;
          pmax = fmaxf(pmax, fmaxf(s0[r], s1[r]));
        }
      } else {
#pragma unroll
        for (int r = 0; r < 16; ++r) pmax = fmaxf(pmax, fmaxf(s0[r], s1[r]));
      }
      pmax = fmaxf(pmax, __shfl_xor(pmax, 32));
      pmax *= SC;                              // into log2 domain

      if (__any(pmax > m + 8.f)) {
        float mn = fmaxf(m, pmax);
        float al = __builtin_amdgcn_exp2f(m - mn);
        m = mn;
        lsum *= al;
#pragma unroll
        for (int r = 0; r < 16; ++r) { o0[r] *= al; o1[r] *= al; }
      }
      float rs = 0.f;
#pragma unroll
      for (int r = 0; r < 16; ++r) {
        float p0 = __builtin_amdgcn_exp2f(__builtin_fmaf(s0[r], SC, -m));
        float p1 = __builtin_amdgcn_exp2f(__builtin_fmaf(s1[r], SC, -m));
        s0[r] = p0; s1[r] = p1;
        rs += p0 + p1;
      }
      rs += __shfl_xor(rs, 32);
      lsum += rs;

      // P^T -> bf16 B-frags (cvt_pk + permlane32_swap, T12)
      bf16x8 pa[4];
#pragma unroll
      for (int sl = 0; sl < 2; ++sl) {
        int wd[8];
#pragma unroll
        for (int i = 0; i < 8; ++i)
          wd[i] = sl ? cvt_pk_bf16(s1[2 * i], s1[2 * i + 1])
                     : cvt_pk_bf16(s0[2 * i], s0[2 * i + 1]);
#pragma unroll
        for (int pp = 0; pp < 2; ++pp) {
          i32x2 r0 = __builtin_amdgcn_permlane32_swap(wd[pp * 4 + 0], wd[pp * 4 + 2], false, false);
          i32x2 r1 = __builtin_amdgcn_permlane32_swap(wd[pp * 4 + 1], wd[pp * 4 + 3], false, false);
          union { int i[4]; bf16x8 v; } u;
          u.i[0] = r0[0]; u.i[1] = r1[0]; u.i[2] = r0[1]; u.i[3] = r1[1];
          pa[sl * 2 + pp] = u.v;
        }
      }

      // O^T += V^T · P^T
      __builtin_amdgcn_s_setprio(1);
#pragma unroll
      for (int ks = 0; ks < 4; ++ks) {
        bf16x8 va0 = *(const bf16x8*)(vb + kfb + ((ks * 32 + h * 16) ^ fsw));
        bf16x8 va1 = *(const bf16x8*)(vb + 4096 + kfb + ((ks * 32 + h * 16) ^ fsw));
        o0 = __builtin_amdgcn_mfma_f32_32x32x16_bf16(va0, pa[ks], o0, 0, 0, 0);
        o1 = __builtin_amdgcn_mfma_f32_32x32x16_bf16(va1, pa[ks], o1, 0, 0, 0);
      }
      __builtin_amdgcn_s_setprio(0);
    }
    __syncthreads();                           // drains stage loads + guards buffers
    cur ^= 1;
  }

  const float inv = 1.f / lsum;
  const int b = bh >> 4, hh = bh & 15;
  ushort_t* yp = Y + ((size_t)(b * 2048 + qg)) * 1024 + hh * 64;
#pragma unroll
  for (int grp = 0; grp < 2; ++grp) {
#pragma unroll
    for (int rg = 0; rg < 4; ++rg) {
      int d0 = grp * 32 + rg * 8 + h * 4;
      u16x4 pk;
#pragma unroll
      for (int j = 0; j < 4; ++j)
        pk[j] = f2bf((grp ? o1[rg * 4 + j] : o0[rg * 4 + j]) * inv);
      *(u16x4*)(yp + d0) = pk;
    }
  }
}

// ---------------- launch ----------------

extern "C" void kernel_launch(void* const* d_in, const int* in_sizes, int n_in,
                              void* d_out, int out_size, void* d_ws, size_t ws_size,
                              hipStream_t stream) {
  const float* x      = (const float*)d_in[0];
  const float* w_qkv  = (const float*)d_in[1];
  const float* b_qkv  = (const float*)d_in[2];
  const float* w_proj = (const float*)d_in[3];
  const float* b_proj = (const float*)d_in[4];
  float* out = (float*)d_out;

  char* ws = (char*)d_ws;
  ushort_t* xb = (ushort_t*)(ws + 0);            // 16 MB  x bf16 [8192][1024]; reused as y after attn
  ushort_t* Wq = (ushort_t*)(ws + (16u << 20));  //  6 MB  w_qkv^T bf16 [3072][1024]
  ushort_t* Wp = (ushort_t*)(ws + (22u << 20));  //  2 MB  w_proj^T bf16 [1024][1024]
  ushort_t* Qh = (ushort_t*)(ws + (24u << 20));  // 16 MB  [64][2048][64]
  ushort_t* Kh = (ushort_t*)(ws + (40u << 20));  // 16 MB
  ushort_t* Vh = (ushort_t*)(ws + (56u << 20));  // 16 MB
  ushort_t* Vt = (ushort_t*)(ws + (72u << 20));  // 16 MB  [64][64][2048]

  cast_kernel<<<8192, 256, 0, stream>>>(x, xb, 2097152);
  transpose_cast<<<dim3(48, 16), 256, 0, stream>>>(w_qkv, Wq, 1024, 3072);
  transpose_cast<<<dim3(16, 16), 256, 0, stream>>>(w_proj, Wp, 1024, 1024);

  gemm_kernel<0><<<dim3(24, 64), 256, 0, stream>>>(xb, Wq, b_qkv, nullptr, Qh, Kh, Vh,
                                                   8192, 3072, 1024);
  transpose_v<<<dim3(32, 64), 256, 0, stream>>>(Vh, Vt);
  attn_kernel<<<512, 512, 0, stream>>>(Qh, Kh, Vt, xb /* y overwrites x_bf16 */);
  gemm_kernel<1><<<dim3(8, 64), 256, 0, stream>>>(xb, Wp, b_proj, out, nullptr, nullptr, nullptr,
                                                  8192, 1024, 1024);
}